// Round 1
// baseline (106.119 us; speedup 1.0000x reference)
//
#include <hip/hip_runtime.h>

// DensityLoss: B=8, N=4096, radius=0.1, NSAMPLE=9, TOPK=5, H=0.12, EPS=1e-12
// Output: scalar mean over [B,N,TOPK-1] of (RADIUS - sqrt(ds)*exp(-ds/H^2))

#define NB 8
#define NPTS 4096
#define NS 9
#define PPB 16          // points (= waves) per block; block = 1024 threads
#define RAD2 0.01f
#define H2 0.0144f
#define EPSV 1e-12f
#define SCALE (1.0f / 131072.0f)   // 1/(B*N*(TOPK-1)) = 1/(8*4096*4)

__global__ __launch_bounds__(1024) void density_loss_kernel(
    const float* __restrict__ pred, float* __restrict__ out) {
    __shared__ float sh[3][NPTS];       // SoA point cloud for this batch (48 KB)
    __shared__ float buf[PPB][NS];      // per-wave neighbor ds slots
    __shared__ float wsum[PPB];

    const int tid  = threadIdx.x;
    const int lane = tid & 63;
    const int wid  = tid >> 6;
    const int b    = blockIdx.x >> 8;               // 256 groups per batch
    const int n    = ((blockIdx.x & 255) << 4) + wid;

    // Stage batch b's points AoS->SoA into LDS (coalesced global reads)
    const float* src = pred + (size_t)b * (NPTS * 3);
    for (int i = tid; i < NPTS * 3; i += 1024) {
        sh[i % 3][i / 3] = src[i];
    }
    __syncthreads();

    const float pnx = sh[0][n];
    const float pny = sh[1][n];
    const float pnz = sh[2][n];

    // Index-ordered scan: collect ds of first NS points with ds <= RAD2.
    int count = 0;  // wave-uniform
    for (int t = 0; t < NPTS / 64; ++t) {
        const int m = (t << 6) + lane;
        float dx = sh[0][m] - pnx;
        float dy = sh[1][m] - pny;
        float dz = sh[2][m] - pnz;
        float ds = fmaf(dz, dz, fmaf(dy, dy, dx * dx));
        bool q = (ds <= RAD2);
        unsigned long long mask = __ballot(q);
        if (mask) {
            if (q) {
                int rank = (int)__popcll(mask & ((1ull << lane) - 1ull));
                int slot = count + rank;
                if (slot < NS) buf[wid][slot] = ds;
            }
            count += (int)__popcll(mask);
            if (count >= NS) break;   // wave-uniform early exit
        }
    }
    __syncthreads();  // buf writes visible; all waves done

    if (lane == 0) {
        int cnt = count > NS ? NS : count;   // cnt >= 1 always (self qualifies)
        float s[NS];
        float first = buf[wid][0];
        #pragma unroll
        for (int j = 0; j < NS; ++j) {
            float v = buf[wid][j];
            s[j] = (j < cnt) ? v : first;    // fill empty slots with first
        }
        // Partial selection sort: smallest 5 ascending into s[0..4]
        #pragma unroll
        for (int i = 0; i < 5; ++i) {
            #pragma unroll
            for (int j = i + 1; j < NS; ++j) {
                float lo = fminf(s[i], s[j]);
                float hi = fmaxf(s[i], s[j]);
                s[i] = lo;
                s[j] = hi;
            }
        }
        // Drop the smallest (s[0]); accumulate terms for s[1..4]
        float acc = 0.0f;
        #pragma unroll
        for (int i = 1; i < 5; ++i) {
            float c = (s[i] < EPSV) ? EPSV : s[i];
            float w = expf(-c / H2);
            acc += 0.1f - sqrtf(c) * w;
        }
        wsum[wid] = acc;
    }
    __syncthreads();

    if (tid == 0) {
        float t = 0.0f;
        #pragma unroll
        for (int i = 0; i < PPB; ++i) t += wsum[i];
        atomicAdd(out, t * SCALE);
    }
}

extern "C" void kernel_launch(void* const* d_in, const int* in_sizes, int n_in,
                              void* d_out, int out_size, void* d_ws, size_t ws_size,
                              hipStream_t stream) {
    const float* pred = (const float*)d_in[0];
    float* out = (float*)d_out;
    // d_out is re-poisoned to 0xAA before every timed launch — zero it ourselves.
    hipMemsetAsync(out, 0, sizeof(float), stream);
    density_loss_kernel<<<dim3(NB * NPTS / PPB), dim3(1024), 0, stream>>>(pred, out);
}

// Round 3
// 102.348 us; speedup vs baseline: 1.0368x; 1.0368x over previous
//
#include <hip/hip_runtime.h>

// DensityLoss: B=8, N=4096, radius=0.1, NSAMPLE=9, TOPK=5, H=0.12, EPS=1e-12
// Output: scalar mean over [B,N,TOPK-1] of (RADIUS - sqrt(ds)*exp(-ds/H^2))

#define NB 8
#define NPTS 4096
#define NS 9
// Component stride 4096+8: 4104 % 32 == 8, so the x/y/z planes start in
// different banks -> staging writes (lanes 3j,3j+1,3j+2 hit planes 0,1,2)
// spread across banks instead of 6-way colliding (R1: 1.57M conflict cycles).
#define STRIDE 4104
#define RAD2 0.01f
#define H2 0.0144f
#define EPSV 1e-12f
#define SCALE (1.0f / 131072.0f)   // 1/(B*N*(TOPK-1)) = 1/(8*4096*4)

__global__ __launch_bounds__(1024) void density_loss_kernel(
    const float* __restrict__ pred, float* __restrict__ out) {
    __shared__ float sh[3 * STRIDE];    // SoA (padded) point cloud, ~48.1 KB
    __shared__ float buf[16][NS];       // per-wave neighbor ds slots
    __shared__ float wsum[16];

    const int tid  = threadIdx.x;
    const int lane = tid & 63;
    const int wid  = tid >> 6;
    const int b    = blockIdx.x >> 8;               // 256 groups per batch
    const int n    = ((blockIdx.x & 255) << 4) + wid;

    // Stage batch b's points AoS->SoA into padded LDS (coalesced global reads)
    const float* src = pred + (size_t)b * (NPTS * 3);
    for (int i = tid; i < NPTS * 3; i += 1024) {
        int c = i % 3, p = i / 3;
        sh[c * STRIDE + p] = src[i];
    }
    __syncthreads();

    const float pnx = sh[n];
    const float pny = sh[STRIDE + n];
    const float pnz = sh[2 * STRIDE + n];

    // Index-ordered scan: collect ds of first NS points with ds <= RAD2.
    // Unroll 4 chunks per iteration: one base address per group; the
    // component/chunk offsets (c*16416 + u*256 bytes <= 33.6KB) fold into the
    // 16-bit ds_read immediate -> ~3 addr VALU per chunk eliminated.
    int count = 0;  // wave-uniform
    for (int tb = 0; tb < NPTS / 256 && count < NS; ++tb) {
        const int m0 = (tb << 8) + lane;
        #pragma unroll
        for (int u = 0; u < 4; ++u) {
            const int m = m0 + (u << 6);
            float dx = sh[m] - pnx;
            float dy = sh[STRIDE + m] - pny;
            float dz = sh[2 * STRIDE + m] - pnz;
            float ds = fmaf(dz, dz, fmaf(dy, dy, dx * dx));
            bool q = (ds <= RAD2);
            unsigned long long mask = __ballot(q);
            if (mask) {
                if (q) {
                    int slot = count + (int)__popcll(mask & ((1ull << lane) - 1ull));
                    if (slot < NS) buf[wid][slot] = ds;   // guarded: group may overshoot
                }
                count += (int)__popcll(mask);
            }
        }
    }
    __syncthreads();  // buf writes visible; all waves done

    if (lane == 0) {
        int cnt = count > NS ? NS : count;   // cnt >= 1 always (self qualifies)
        float s[NS];
        float first = buf[wid][0];
        #pragma unroll
        for (int j = 0; j < NS; ++j) {
            float v = buf[wid][j];
            s[j] = (j < cnt) ? v : first;    // fill empty slots with first
        }
        // Partial selection sort: smallest 5 ascending into s[0..4]
        #pragma unroll
        for (int i = 0; i < 5; ++i) {
            #pragma unroll
            for (int j = i + 1; j < NS; ++j) {
                float lo = fminf(s[i], s[j]);
                float hi = fmaxf(s[i], s[j]);
                s[i] = lo;
                s[j] = hi;
            }
        }
        // Drop the smallest (s[0]); accumulate terms for s[1..4]
        float acc = 0.0f;
        #pragma unroll
        for (int i = 1; i < 5; ++i) {
            float c = (s[i] < EPSV) ? EPSV : s[i];
            float w = expf(-c / H2);
            acc += 0.1f - sqrtf(c) * w;
        }
        wsum[wid] = acc;
    }
    __syncthreads();

    if (tid == 0) {
        float t = 0.0f;
        #pragma unroll
        for (int i = 0; i < 16; ++i) t += wsum[i];
        atomicAdd(out, t * SCALE);
    }
}

extern "C" void kernel_launch(void* const* d_in, const int* in_sizes, int n_in,
                              void* d_out, int out_size, void* d_ws, size_t ws_size,
                              hipStream_t stream) {
    const float* pred = (const float*)d_in[0];
    float* out = (float*)d_out;
    // d_out is re-poisoned to 0xAA before every timed launch — zero it ourselves.
    hipMemsetAsync(out, 0, sizeof(float), stream);
    density_loss_kernel<<<dim3(NB * NPTS / 16), dim3(1024), 0, stream>>>(pred, out);
}

// Round 4
// 91.862 us; speedup vs baseline: 1.1552x; 1.1141x over previous
//
#include <hip/hip_runtime.h>

// DensityLoss: B=8, N=4096, radius=0.1, NSAMPLE=9, TOPK=5, H=0.12, EPS=1e-12
// Output: scalar mean over [B,N,TOPK-1] of (RADIUS - sqrt(ds)*exp(-ds/H^2))

#define NB 8
#define NPTS 4096
#define NS 9
// STRIDE*4 = 16640 B = 65*256: every plane offset and chunk offset is a
// multiple of 256 B -> backend can merge paired ds_read_b32 into
// ds_read2st64_b32 off one shared vaddr. Scan reads are stride-4B (2
// lanes/bank, free). Staging writes are ds_write_b128 contiguous ->
// conflict-free (R3 residual 786K conflict cycles came from scalar staging).
#define STRIDE 4160
#define RAD2 0.01f
#define H2 0.0144f
#define EPSV 1e-12f
#define SCALE (1.0f / 131072.0f)   // 1/(B*N*(TOPK-1)) = 1/(8*4096*4)

typedef float v2f __attribute__((ext_vector_type(2)));

__global__ __launch_bounds__(1024) void density_loss_kernel(
    const float* __restrict__ pred, float* __restrict__ out) {
    __shared__ float sh[3 * STRIDE];    // SoA (padded) point cloud, ~48.8 KB
    __shared__ float buf[16][NS];       // per-wave neighbor ds slots
    __shared__ float wsum[16];

    const int tid  = threadIdx.x;
    const int lane = tid & 63;
    const int wid  = tid >> 6;
    const int b    = blockIdx.x >> 8;               // 256 groups per batch
    const int n    = ((blockIdx.x & 255) << 4) + wid;

    // Stage batch b: AoS global -> SoA LDS, vectorized both sides.
    // Thread t loads points 4t..4t+3 (3x dwordx4, coalesced), transposes in
    // registers, stores one float4 per plane (ds_write_b128, conflict-free).
    {
        const float4* s4 = (const float4*)(pred + (size_t)b * (NPTS * 3));
        float4 A = s4[3 * tid];
        float4 Bq = s4[3 * tid + 1];
        float4 Cq = s4[3 * tid + 2];
        float4 xs = {A.x, A.w, Bq.z, Cq.y};
        float4 ys = {A.y, Bq.x, Bq.w, Cq.z};
        float4 zs = {A.z, Bq.y, Cq.x, Cq.w};
        *(float4*)(sh + 4 * tid)              = xs;
        *(float4*)(sh + STRIDE + 4 * tid)     = ys;
        *(float4*)(sh + 2 * STRIDE + 4 * tid) = zs;
    }
    __syncthreads();

    const float pnx = sh[n];
    const float pny = sh[STRIDE + n];
    const float pnz = sh[2 * STRIDE + n];
    const v2f px2 = {pnx, pnx}, py2 = {pny, pny}, pz2 = {pnz, pnz};

    // Index-ordered scan, 4 chunks (256 candidates) per group, processed as
    // 2 chunk-pairs with packed (v2f) math. Rank via v_mbcnt. Early exit
    // checked per group (wave-uniform).
    int count = 0;
    const float* pl = sh + lane;
    for (int g = 0; g < NPTS / 256 && count < NS; ++g, pl += 256) {
        #pragma unroll
        for (int h = 0; h < 2; ++h) {
            const int o = h * 128;
            v2f xa = {pl[o],              pl[o + 64]};
            v2f ya = {pl[STRIDE + o],     pl[STRIDE + o + 64]};
            v2f za = {pl[2 * STRIDE + o], pl[2 * STRIDE + o + 64]};
            v2f dx = xa - px2, dy = ya - py2, dz = za - pz2;
            v2f ds2 = dx * dx + dy * dy + dz * dz;
            bool q0 = (ds2.x <= RAD2);
            bool q1 = (ds2.y <= RAD2);
            unsigned long long m0 = __ballot(q0);
            unsigned long long m1 = __ballot(q1);
            if (m0) {
                if (q0) {
                    unsigned r = __builtin_amdgcn_mbcnt_lo((unsigned)m0, 0u);
                    r = __builtin_amdgcn_mbcnt_hi((unsigned)(m0 >> 32), r);
                    int slot = count + (int)r;
                    if (slot < NS) buf[wid][slot] = ds2.x;
                }
                count += (int)__popcll(m0);
            }
            if (m1) {
                if (q1) {
                    unsigned r = __builtin_amdgcn_mbcnt_lo((unsigned)m1, 0u);
                    r = __builtin_amdgcn_mbcnt_hi((unsigned)(m1 >> 32), r);
                    int slot = count + (int)r;
                    if (slot < NS) buf[wid][slot] = ds2.y;
                }
                count += (int)__popcll(m1);
            }
        }
    }
    __syncthreads();  // buf writes visible; all waves done

    if (lane == 0) {
        int cnt = count > NS ? NS : count;   // cnt >= 1 always (self qualifies)
        float s[NS];
        float first = buf[wid][0];
        #pragma unroll
        for (int j = 0; j < NS; ++j) {
            float v = buf[wid][j];
            s[j] = (j < cnt) ? v : first;    // fill empty slots with first
        }
        // Partial selection sort: smallest 5 ascending into s[0..4]
        #pragma unroll
        for (int i = 0; i < 5; ++i) {
            #pragma unroll
            for (int j = i + 1; j < NS; ++j) {
                float lo = fminf(s[i], s[j]);
                float hi = fmaxf(s[i], s[j]);
                s[i] = lo;
                s[j] = hi;
            }
        }
        // Drop the smallest (s[0]); accumulate terms for s[1..4]
        float acc = 0.0f;
        #pragma unroll
        for (int i = 1; i < 5; ++i) {
            float c = (s[i] < EPSV) ? EPSV : s[i];
            float w = expf(-c / H2);
            acc += 0.1f - sqrtf(c) * w;
        }
        wsum[wid] = acc;
    }
    __syncthreads();

    if (tid == 0) {
        float t = 0.0f;
        #pragma unroll
        for (int i = 0; i < 16; ++i) t += wsum[i];
        atomicAdd(out, t * SCALE);
    }
}

extern "C" void kernel_launch(void* const* d_in, const int* in_sizes, int n_in,
                              void* d_out, int out_size, void* d_ws, size_t ws_size,
                              hipStream_t stream) {
    const float* pred = (const float*)d_in[0];
    float* out = (float*)d_out;
    // d_out is re-poisoned to 0xAA before every timed launch — zero it ourselves.
    hipMemsetAsync(out, 0, sizeof(float), stream);
    density_loss_kernel<<<dim3(NB * NPTS / 16), dim3(1024), 0, stream>>>(pred, out);
}

// Round 5
// 73.842 us; speedup vs baseline: 1.4371x; 1.2440x over previous
//
#include <hip/hip_runtime.h>

// DensityLoss: B=8, N=4096, radius=0.1, NSAMPLE=9, TOPK=5, H=0.12, EPS=1e-12
// Output: scalar mean over [B,N,TOPK-1] of (RADIUS - sqrt(ds)*exp(-ds/H^2))
//
// R5 structure: 4 query points per wave (coords wave-uniform -> SGPRs),
// ds_read_b128 cloud reads. LDS layout is block-transposed SoA: candidate c
// stored at p(c) = (c & ~255) + ((c&63)<<2) + ((c>>6)&3), so lane L's float4
// in block g = candidates {g*256+L, +64, +128, +192}: component k is an
// index-contiguous sub-chunk with linear lane map -> R4's exact
// ballot/mbcnt first-9-by-index rank logic carries over unchanged.

#define NB 8
#define NPTS 4096
#define NS 9
#define RAD2 0.01f
#define H2 0.0144f
#define EPSV 1e-12f
#define SCALE (1.0f / 131072.0f)   // 1/(B*N*(TOPK-1)) = 1/(8*4096*4)

typedef float v2f __attribute__((ext_vector_type(2)));

__device__ __forceinline__ void step(float val, int& cnt, float* row) {
    bool q = (val <= RAD2);
    unsigned long long m = __ballot(q);
    if (m) {                       // wave-uniform (SGPR) -> s_cbranch
        if (q) {                   // exec-masked
            unsigned r = __builtin_amdgcn_mbcnt_lo((unsigned)m, 0u);
            r = __builtin_amdgcn_mbcnt_hi((unsigned)(m >> 32), r);
            int slot = cnt + (int)r;
            if (slot < NS) row[slot] = val;
        }
        cnt += (int)__popcll(m);   // scalar (s_bcnt1)
    }
}

__global__ __launch_bounds__(1024) void density_loss_kernel(
    const float* __restrict__ pred, float* __restrict__ out) {
    __shared__ __align__(16) float sh[3 * NPTS];   // 48 KB transposed SoA
    __shared__ __align__(16) float buf[64][NS];    // per-point neighbor slots
    __shared__ __align__(16) int cnts[64];

    const int tid   = threadIdx.x;
    const int lane  = tid & 63;
    const int wid   = tid >> 6;
    const int b     = blockIdx.x >> 6;                       // 64 blocks/batch
    const int nbase = ((blockIdx.x & 63) << 6) + (wid << 2); // 4 queries/wave

    // ---- Stage: strided global float3 reads -> contiguous b128 LDS writes.
    // Thread t fills positions 4t..4t+3 of each plane = candidates
    // cbase+64k, cbase = (t>>6)*256 + (t&63). Writes are conflict-free b128.
    {
        const float* src = pred + (size_t)b * (NPTS * 3);
        const int cbase = (wid << 8) + lane;
        float xs[4], ys[4], zs[4];
        #pragma unroll
        for (int k = 0; k < 4; ++k) {
            const float* p = src + 3 * (cbase + (k << 6));
            xs[k] = p[0]; ys[k] = p[1]; zs[k] = p[2];
        }
        *(float4*)(sh + (tid << 2))            = (float4){xs[0], xs[1], xs[2], xs[3]};
        *(float4*)(sh + NPTS + (tid << 2))     = (float4){ys[0], ys[1], ys[2], ys[3]};
        *(float4*)(sh + 2 * NPTS + (tid << 2)) = (float4){zs[0], zs[1], zs[2], zs[3]};
    }
    __syncthreads();

    // Query coords (wave-uniform -> scalarizable)
    float qx[4], qy[4], qz[4];
    #pragma unroll
    for (int q = 0; q < 4; ++q) {
        int n = nbase + q;
        int p = (n & ~255) | ((n & 63) << 2) | ((n >> 6) & 3);
        qx[q] = sh[p]; qy[q] = sh[NPTS + p]; qz[q] = sh[2 * NPTS + p];
    }

    // ---- Scan: 256 candidates/iteration via 3x ds_read_b128, shared
    // across the wave's 4 query points. Sub-chunks k=0..3 processed in
    // index order; per-point early-skip and wave early-exit.
    int c0 = 0, c1 = 0, c2 = 0, c3 = 0;
    const float* pl = sh + (lane << 2);
    for (int g = 0; g < NPTS / 256; ++g, pl += 256) {
        float4 xa = *(const float4*)pl;
        float4 ya = *(const float4*)(pl + NPTS);
        float4 za = *(const float4*)(pl + 2 * NPTS);
        v2f xl = {xa.x, xa.y}, xh = {xa.z, xa.w};
        v2f yl = {ya.x, ya.y}, yh = {ya.z, ya.w};
        v2f zl = {za.x, za.y}, zh = {za.z, za.w};
        #pragma unroll
        for (int q = 0; q < 4; ++q) {
            int& cq = (q == 0) ? c0 : (q == 1) ? c1 : (q == 2) ? c2 : c3;
            if (cq >= NS) continue;          // wave-uniform skip (point done)
            v2f px = {qx[q], qx[q]}, py = {qy[q], qy[q]}, pz = {qz[q], qz[q]};
            v2f dxl = xl - px, dyl = yl - py, dzl = zl - pz;
            v2f dxh = xh - px, dyh = yh - py, dzh = zh - pz;
            v2f dl = dxl * dxl + dyl * dyl + dzl * dzl;
            v2f dh = dxh * dxh + dyh * dyh + dzh * dzh;
            float* row = buf[(wid << 2) + q];
            step(dl.x, cq, row);
            step(dl.y, cq, row);
            step(dh.x, cq, row);
            step(dh.y, cq, row);
        }
        if (c0 >= NS && c1 >= NS && c2 >= NS && c3 >= NS) break;
    }
    if (lane == 0)
        *(int4*)(cnts + (wid << 2)) = (int4){c0, c1, c2, c3};
    __syncthreads();

    // ---- Epilogue: wave 0, lane i handles point nbase_block+i.
    if (tid < 64) {
        int cnt = cnts[tid]; if (cnt > NS) cnt = NS;   // cnt >= 1 (self)
        float s[NS];
        float first = buf[tid][0];
        #pragma unroll
        for (int j = 0; j < NS; ++j) {
            float v = buf[tid][j];
            s[j] = (j < cnt) ? v : first;
        }
        // Partial selection sort: smallest 5 ascending into s[0..4]
        #pragma unroll
        for (int i = 0; i < 5; ++i) {
            #pragma unroll
            for (int j = i + 1; j < NS; ++j) {
                float lo = fminf(s[i], s[j]);
                float hi = fmaxf(s[i], s[j]);
                s[i] = lo; s[j] = hi;
            }
        }
        float acc = 0.0f;
        #pragma unroll
        for (int i = 1; i < 5; ++i) {
            float c = (s[i] < EPSV) ? EPSV : s[i];
            acc += 0.1f - sqrtf(c) * expf(-c / H2);
        }
        #pragma unroll
        for (int off = 32; off >= 1; off >>= 1)
            acc += __shfl_down(acc, off, 64);
        if (tid == 0) atomicAdd(out, acc * SCALE);
    }
}

extern "C" void kernel_launch(void* const* d_in, const int* in_sizes, int n_in,
                              void* d_out, int out_size, void* d_ws, size_t ws_size,
                              hipStream_t stream) {
    const float* pred = (const float*)d_in[0];
    float* out = (float*)d_out;
    // d_out is re-poisoned to 0xAA before every timed launch — zero it ourselves.
    hipMemsetAsync(out, 0, sizeof(float), stream);
    density_loss_kernel<<<dim3(NB * 64), dim3(1024), 0, stream>>>(pred, out);
}